// Round 1
// baseline (5099.022 us; speedup 1.0000x reference)
//
#include <hip/hip_runtime.h>
#include <hip/hip_bf16.h>
#include <math.h>

// ---------------- problem constants ----------------
#define B_      2
#define L_      1024
#define HID     2048
#define T_      (B_*L_)      // 2048 tokens
#define NH      32
#define HD      64
#define NKV     8
#define INTER   8192
#define DSSM    2048
#define MH      32
#define MP      64
#define MS      64
#define MK      4
#define CONV_DIM 2176
#define QKV_N   3072
#define INPROJ_N 4256

typedef __bf16 bf16x8 __attribute__((ext_vector_type(8)));
typedef float  floatx4 __attribute__((ext_vector_type(4)));

// ---------------- workspace layout (float elements) ----------------
// arena: phase-1 (attn+ssm) buffers, later aliased by phase-2 (mlp) buffers
static const size_t OFF_HSLN = 0;            // 4194304  (B,L,HID) rms'd input
static const size_t OFF_QKV  = 4194304;      // 6291456
static const size_t OFF_Q    = 10485760;     // 4194304
static const size_t OFF_K    = 14680064;     // 1048576
static const size_t OFF_V    = 15728640;     // 1048576
static const size_t OFF_ATTN = 16777216;     // 4194304  attention out (pre o-proj)
static const size_t OFF_PROJ = 20971520;     // 8716288  in_proj out
static const size_t OFF_XBC  = 29687808;     // 4456448  conv+silu out
static const size_t OFF_Y    = 34144256;     // 4194304  scan out
static const size_t OFF_G    = 38338560;     // 4194304  gated+rms'd
// phase-2 aliases (safe: all phase-1 buffers dead by first overlapping write)
static const size_t OFF_HS2  = 0;            // 4194304
static const size_t OFF_GU   = 4194304;      // 33554432
static const size_t OFF_ACT  = 37748864;     // 16777216
static const size_t ARENA_END = 54526080;
static const size_t OFF_H2   = ARENA_END;            // 4194304 residual stream
static const size_t OFF_MUP  = ARENA_END + 4194304;  // 4256
// total: 58,724,640 floats = 234.9 MB

// ---------------- helpers ----------------
__device__ inline float block_sum(float v, float* red) {
#pragma unroll
  for (int o = 32; o > 0; o >>= 1) v += __shfl_down(v, o, 64);
  const int lane = threadIdx.x & 63, wv = threadIdx.x >> 6;
  if (lane == 0) red[wv] = v;
  __syncthreads();
  if (threadIdx.x == 0) red[0] = red[0] + red[1] + red[2] + red[3];
  __syncthreads();
  float r = red[0];
  __syncthreads();
  return r;
}

__device__ inline float block_max(float v, float* red) {
#pragma unroll
  for (int o = 32; o > 0; o >>= 1) v = fmaxf(v, __shfl_down(v, o, 64));
  const int lane = threadIdx.x & 63, wv = threadIdx.x >> 6;
  if (lane == 0) red[wv] = v;
  __syncthreads();
  if (threadIdx.x == 0) red[0] = fmaxf(fmaxf(red[0], red[1]), fmaxf(red[2], red[3]));
  __syncthreads();
  float r = red[0];
  __syncthreads();
  return r;
}

__device__ inline void cvt8(__bf16* dst, float4 a, float4 b) {
  bf16x8 v;
  v[0] = (__bf16)a.x; v[1] = (__bf16)a.y; v[2] = (__bf16)a.z; v[3] = (__bf16)a.w;
  v[4] = (__bf16)b.x; v[5] = (__bf16)b.y; v[6] = (__bf16)b.z; v[7] = (__bf16)b.w;
  *(bf16x8*)dst = v;
}

// ---------------- GEMM: out[m,n] = alpha*colscale[n]*sum_k A[m,k]*W[n,k] + addin[m,n]
// M fixed = gridDim.x*128 (always 2048 here). 128x128 tile, BK=32, bf16 MFMA fp32-acc.
#define GTM 128
#define GTN 128
#define GTK 32
#define LDSP 40   // padded LDS row (bf16 elems): 80B stride keeps 16B align, 2-way banks (free)

__global__ __launch_bounds__(256) void gemm_kernel(
    const float* __restrict__ A, const float* __restrict__ W,
    float* __restrict__ out, const float* __restrict__ addin,
    const float* __restrict__ colscale,
    int N, int K, int ldo, float alpha)
{
  __shared__ __align__(16) __bf16 As[GTM * LDSP];
  __shared__ __align__(16) __bf16 Bs[GTN * LDSP];
  const int tid = threadIdx.x;
  const int m0 = blockIdx.x * GTM;
  const int n0 = blockIdx.y * GTN;
  const int lane = tid & 63;
  const int wave = tid >> 6;
  const int wm = (wave >> 1) * 64;
  const int wn = (wave & 1) * 64;
  const int fr = lane & 15;
  const int fq = lane >> 4;

  const int sr = tid >> 1;          // staged row 0..127
  const int sk = (tid & 1) << 4;    // k offset 0/16
  const float* Ap = A + (size_t)(m0 + sr) * K + sk;
  const int nrow = n0 + sr;
  const float* Wp = W + (size_t)nrow * K + sk;
  const bool nvalid = (nrow < N);

  floatx4 acc[4][4];
#pragma unroll
  for (int i = 0; i < 4; i++)
#pragma unroll
    for (int j = 0; j < 4; j++) acc[i][j] = (floatx4){0.f, 0.f, 0.f, 0.f};

  for (int k0 = 0; k0 < K; k0 += GTK) {
    const float4* ap = (const float4*)(Ap + k0);
    float4 a0 = ap[0], a1 = ap[1], a2 = ap[2], a3 = ap[3];
    float4 b0, b1, b2, b3;
    if (nvalid) {
      const float4* wp = (const float4*)(Wp + k0);
      b0 = wp[0]; b1 = wp[1]; b2 = wp[2]; b3 = wp[3];
    } else {
      b0 = b1 = b2 = b3 = make_float4(0.f, 0.f, 0.f, 0.f);
    }
    cvt8(&As[sr * LDSP + sk], a0, a1);
    cvt8(&As[sr * LDSP + sk + 8], a2, a3);
    cvt8(&Bs[sr * LDSP + sk], b0, b1);
    cvt8(&Bs[sr * LDSP + sk + 8], b2, b3);
    __syncthreads();

    bf16x8 aF[4], bF[4];
#pragma unroll
    for (int i = 0; i < 4; i++)
      aF[i] = *(const bf16x8*)&As[(wm + i * 16 + fr) * LDSP + fq * 8];
#pragma unroll
    for (int j = 0; j < 4; j++)
      bF[j] = *(const bf16x8*)&Bs[(wn + j * 16 + fr) * LDSP + fq * 8];
#pragma unroll
    for (int i = 0; i < 4; i++)
#pragma unroll
      for (int j = 0; j < 4; j++)
        acc[i][j] = __builtin_amdgcn_mfma_f32_16x16x32_bf16(aF[i], bF[j], acc[i][j], 0, 0, 0);
    __syncthreads();
  }

  // epilogue: C/D layout col=lane&15, row=(lane>>4)*4+r  [verified m89/m91]
#pragma unroll
  for (int i = 0; i < 4; i++) {
#pragma unroll
    for (int r = 0; r < 4; r++) {
      const int m = m0 + wm + i * 16 + fq * 4 + r;
      float* orow = out + (size_t)m * ldo;
      const float* arow = addin ? (addin + (size_t)m * ldo) : nullptr;
#pragma unroll
      for (int j = 0; j < 4; j++) {
        const int n = n0 + wn + j * 16 + fr;
        if (n < N) {
          float vv = acc[i][j][r] * alpha;
          if (colscale) vv *= colscale[n];
          if (arow) vv += arow[n];
          orow[n] = vv;
        }
      }
    }
  }
}

// ---------------- RMSNorm (optionally also copies raw input to `copy`) ----------------
__global__ __launch_bounds__(256) void rms_kernel(
    const float* __restrict__ in, const float* __restrict__ w,
    float* __restrict__ outp, float* __restrict__ copy)
{
  __shared__ float buf[HID];
  __shared__ float red[8];
  const int tid = threadIdx.x;
  const size_t t = blockIdx.x;
  const float* row = in + t * HID;
  float ss = 0.f;
  for (int i = tid; i < HID; i += 256) { float x = row[i]; buf[i] = x; ss += x * x; }
  float tot = block_sum(ss, red);
  float inv = rsqrtf(tot / (float)HID + 1e-5f);
  for (int i = tid; i < HID; i += 256) {
    float x = buf[i];
    outp[t * HID + i] = x * inv * w[i];
    if (copy) copy[t * HID + i] = x;
  }
}

// ---------------- mup column-scale vector ----------------
__global__ void mup_kernel(float* __restrict__ mup) {
  int i = blockIdx.x * 256 + threadIdx.x;
  if (i >= INPROJ_N) return;
  float v = (i < DSSM) ? 1.0f
          : (i < 2 * DSSM) ? 0.9f
          : (i < 2 * DSSM + MS) ? 0.8f
          : (i < 2 * DSSM + 2 * MS) ? 1.1f
          : 1.2f;
  mup[i] = v;
}

// ---------------- RoPE + split qkv ----------------
__global__ __launch_bounds__(256) void rope_kernel(
    const float* __restrict__ qkv, const int* __restrict__ positions,
    float* __restrict__ q, float* __restrict__ k, float* __restrict__ v)
{
  __shared__ float inv_s[32];
  const int tid = threadIdx.x;
  const size_t t = blockIdx.x;
  const int l = (int)(t & (L_ - 1));
  if (tid < 32) inv_s[tid] = powf(1.0e11f, -(float)(2 * tid) / 64.f);
  __syncthreads();
  const float pos = (float)positions[l];
  const float* src = qkv + t * QKV_N;
  for (int idx = tid; idx < 1536; idx += 256) {
    int head = idx >> 5, hd = idx & 31;
    if (head < 32) {
      float ang = pos * inv_s[hd];
      float c = cosf(ang), sn = sinf(ang);
      float x1 = src[head * 64 + hd], x2 = src[head * 64 + 32 + hd];
      float* dst = q + (t * NH + head) * HD;
      dst[hd] = x1 * c - x2 * sn;
      dst[hd + 32] = x2 * c + x1 * sn;
    } else if (head < 40) {
      int kk = head - 32;
      float ang = pos * inv_s[hd];
      float c = cosf(ang), sn = sinf(ang);
      float x1 = src[2048 + kk * 64 + hd] * 0.7f;
      float x2 = src[2048 + kk * 64 + 32 + hd] * 0.7f;
      float* dst = k + (t * NKV + kk) * HD;
      dst[hd] = x1 * c - x2 * sn;
      dst[hd + 32] = x2 * c + x1 * sn;
    } else {
      int vv = head - 40;
      float* dst = v + (t * NKV + vv) * HD;
      dst[hd] = src[2560 + vv * 64 + hd];
      dst[hd + 32] = src[2560 + vv * 64 + 32 + hd];
    }
  }
}

// ---------------- causal GQA attention, 8 queries per block, fp32 ----------------
__global__ __launch_bounds__(256) void attn_kernel(
    const float* __restrict__ q, const float* __restrict__ k,
    const float* __restrict__ v, float* __restrict__ out)
{
  __shared__ float q_s[8 * 64];
  __shared__ float sc[8 * 1024];
  __shared__ float red[8];
  __shared__ float sinv[8];
  __shared__ float pvred[256];
  const int tid = threadIdx.x;
  const int l0 = blockIdx.x * 8;
  const int h = blockIdx.y;
  const int b = blockIdx.z;
  const int g = h >> 2;   // NH/NKV = 4
  const int nk = l0 + 8;  // keys 0..l0+7 (per-row causal limit applied below)

  for (int i = tid; i < 512; i += 256) {
    int qi = i >> 6, d = i & 63;
    q_s[i] = q[(((size_t)(b * L_ + l0 + qi)) * NH + h) * HD + d];
  }
  __syncthreads();

  // scores: each thread owns keys m = tid, tid+256, ...
  for (int m = tid; m < nk; m += 256) {
    const float4* kp = (const float4*)&k[(((size_t)(b * L_ + m)) * NKV + g) * HD];
    float s[8] = {0.f, 0.f, 0.f, 0.f, 0.f, 0.f, 0.f, 0.f};
#pragma unroll
    for (int d4 = 0; d4 < 16; d4++) {
      float4 kk = kp[d4];
#pragma unroll
      for (int qi = 0; qi < 8; qi++) {
        const float4 qq = *(const float4*)&q_s[qi * 64 + d4 * 4];
        s[qi] += kk.x * qq.x + kk.y * qq.y + kk.z * qq.z + kk.w * qq.w;
      }
    }
#pragma unroll
    for (int qi = 0; qi < 8; qi++) sc[qi * 1024 + m] = s[qi] * 0.125f;
  }
  __syncthreads();

  // per-row softmax (max/sum over m <= l0+qi)
  for (int qi = 0; qi < 8; qi++) {
    const int lim = l0 + qi;
    float lm = -3.0e38f;
    for (int m = tid; m <= lim; m += 256) lm = fmaxf(lm, sc[qi * 1024 + m]);
    float mx = block_max(lm, red);
    float ls = 0.f;
    for (int m = tid; m <= lim; m += 256) {
      float e = __expf(sc[qi * 1024 + m] - mx);
      sc[qi * 1024 + m] = e;
      ls += e;
    }
    float dn = block_sum(ls, red);
    if (tid == 0) sinv[qi] = 1.f / dn;
  }
  __syncthreads();

  // PV: thread (d = tid&63, part = tid>>6)
  const int d = tid & 63, part = tid >> 6;
  float acc[8] = {0.f, 0.f, 0.f, 0.f, 0.f, 0.f, 0.f, 0.f};
  for (int m = part; m < nk; m += 4) {
    float vv = v[(((size_t)(b * L_ + m)) * NKV + g) * HD + d];
#pragma unroll
    for (int qi = 0; qi < 8; qi++)
      if (m <= l0 + qi) acc[qi] += sc[qi * 1024 + m] * vv;
  }
  for (int qi = 0; qi < 8; qi++) {
    pvred[tid] = acc[qi];
    __syncthreads();
    if (tid < 64) {
      float o = (pvred[tid] + pvred[tid + 64] + pvred[tid + 128] + pvred[tid + 192]) * sinv[qi];
      out[((size_t)(b * L_ + l0 + qi)) * HID + h * HD + tid] = o;
    }
    __syncthreads();
  }
}

// ---------------- exact-fp32 recompute of the 32 dt columns of in_proj ----------------
__global__ __launch_bounds__(256) void dtfix_kernel(
    const float* __restrict__ hs_ln, const float* __restrict__ w, float* __restrict__ proj)
{
  const size_t t = blockIdx.x;
  const int tid = threadIdx.x;
  const int o = tid >> 3, part = tid & 7;
  const float* a = hs_ln + t * HID;
  const float* wr = w + (size_t)(INPROJ_N - MH + o) * HID;
  float s = 0.f;
  for (int kk = part * 4; kk < HID; kk += 32) {
    const float4 av = *(const float4*)&a[kk];
    const float4 wv = *(const float4*)&wr[kk];
    s += av.x * wv.x + av.y * wv.y + av.z * wv.z + av.w * wv.w;
  }
  s += __shfl_xor(s, 1);
  s += __shfl_xor(s, 2);
  s += __shfl_xor(s, 4);
  if (part == 0) proj[t * INPROJ_N + (INPROJ_N - MH) + o] = s * 1.32f; // SSM_IN*mup_dt
}

// ---------------- depthwise causal conv (MK=4) + bias + silu ----------------
__global__ __launch_bounds__(256) void conv_kernel(
    const float* __restrict__ proj, const float* __restrict__ cw,
    const float* __restrict__ cb, float* __restrict__ xbc)
{
  const int c = blockIdx.x * 256 + threadIdx.x;
  if (c >= CONV_DIM) return;
  const int t = blockIdx.y;
  const int l = t & (L_ - 1);
  float acc = cb[c];
#pragma unroll
  for (int kk = 0; kk < MK; kk++) {
    int lp = l - (MK - 1) + kk;
    if (lp >= 0)
      acc += proj[((size_t)(t - (MK - 1) + kk)) * INPROJ_N + DSSM + c] * cw[c * MK + kk];
  }
  xbc[(size_t)t * CONV_DIM + c] = acc / (1.f + __expf(-acc));
}

// ---------------- Mamba2 selective scan: one block per (h, b) ----------------
__global__ __launch_bounds__(256) void scan_kernel(
    const float* __restrict__ xbc, const float* __restrict__ proj,
    const float* __restrict__ A_log, const float* __restrict__ dt_bias,
    const float* __restrict__ Dp, float* __restrict__ y)
{
  const int tid = threadIdx.x;
  const int h = blockIdx.x;
  const int b = blockIdx.y;
  const int p = tid >> 2;
  const int j = tid & 3;
  const int si = j * 16;
  const float Ah = -expf(A_log[h]);
  const float dtb = dt_bias[h];
  const float Dh = Dp[h];
  __shared__ float xs[64], Bs[64], Cs[64];
  __shared__ float dts;
  float st[16];
#pragma unroll
  for (int i = 0; i < 16; i++) st[i] = 0.f;

  for (int l = 0; l < L_; l++) {
    const size_t base = (size_t)b * L_ + l;
    if (tid < 64) xs[tid] = xbc[base * CONV_DIM + h * 64 + tid];
    else if (tid < 128) Bs[tid - 64] = xbc[base * CONV_DIM + DSSM + (tid - 64)];
    else if (tid < 192) Cs[tid - 128] = xbc[base * CONV_DIM + DSSM + MS + (tid - 128)];
    else if (tid == 192) dts = proj[base * INPROJ_N + (INPROJ_N - MH) + h];
    __syncthreads();

    float dtv = dts + dtb;
    dtv = (dtv > 20.f) ? dtv : log1pf(expf(dtv));   // softplus
    float dA = expf(dtv * Ah);
    float dtx = dtv * xs[p];
    float ys = 0.f;
#pragma unroll
    for (int i = 0; i < 16; i++) {
      st[i] = st[i] * dA + dtx * Bs[si + i];
      ys += st[i] * Cs[si + i];
    }
    ys += __shfl_xor(ys, 1);
    ys += __shfl_xor(ys, 2);
    if (j == 0) y[base * DSSM + h * 64 + p] = ys + Dh * xs[p];
    __syncthreads();
  }
}

// ---------------- gating (y * silu(z)) + RMSNorm ----------------
__global__ __launch_bounds__(256) void gating_kernel(
    const float* __restrict__ y, const float* __restrict__ proj,
    const float* __restrict__ nw, float* __restrict__ g)
{
  __shared__ float buf[DSSM];
  __shared__ float red[8];
  const int tid = threadIdx.x;
  const size_t t = blockIdx.x;
  float ss = 0.f;
  for (int i = tid; i < DSSM; i += 256) {
    float zv = proj[t * INPROJ_N + i];
    float yv = y[t * DSSM + i];
    float gv = yv * zv / (1.f + __expf(-zv));
    buf[i] = gv;
    ss += gv * gv;
  }
  float tot = block_sum(ss, red);
  float inv = rsqrtf(tot / (float)DSSM + 1e-5f);
  for (int i = tid; i < DSSM; i += 256) g[t * DSSM + i] = buf[i] * inv * nw[i];
}

// ---------------- SwiGLU activation ----------------
__global__ __launch_bounds__(256) void act_kernel(
    const float* __restrict__ gu, float* __restrict__ act)
{
  const int i = blockIdx.x * 256 + threadIdx.x;  // 0..8191
  const size_t t = blockIdx.y;
  float gt = gu[t * (2 * INTER) + i] * 0.9f;     // GATE_MULT
  float up = gu[t * (2 * INTER) + INTER + i];
  act[t * INTER + i] = gt / (1.f + __expf(-gt)) * up;
}

// ---------------- launcher ----------------
extern "C" void kernel_launch(void* const* d_in, const int* in_sizes, int n_in,
                              void* d_out, int out_size, void* d_ws, size_t ws_size,
                              hipStream_t stream)
{
  const float* hidden      = (const float*)d_in[0];
  const int*   positions   = (const int*)d_in[1];
  const float* w_in_ln     = (const float*)d_in[2];
  const float* qkv_w       = (const float*)d_in[3];
  const float* o_w         = (const float*)d_in[4];
  const float* in_proj_w   = (const float*)d_in[5];
  const float* conv_w      = (const float*)d_in[6];
  const float* conv_b      = (const float*)d_in[7];
  const float* A_log       = (const float*)d_in[8];
  const float* dt_bias     = (const float*)d_in[9];
  const float* Dp          = (const float*)d_in[10];
  const float* ssm_norm_w  = (const float*)d_in[11];
  const float* out_proj_w  = (const float*)d_in[12];
  const float* w_pre_ff_ln = (const float*)d_in[13];
  const float* gate_up_w   = (const float*)d_in[14];
  const float* down_w      = (const float*)d_in[15];
  (void)in_sizes; (void)n_in; (void)out_size; (void)ws_size;

  float* ws   = (float*)d_ws;
  float* outp = (float*)d_out;

  float* hs_ln = ws + OFF_HSLN;
  float* qkv   = ws + OFF_QKV;
  float* q     = ws + OFF_Q;
  float* k     = ws + OFF_K;
  float* v     = ws + OFF_V;
  float* attn  = ws + OFF_ATTN;
  float* proj  = ws + OFF_PROJ;
  float* xbc   = ws + OFF_XBC;
  float* y     = ws + OFF_Y;
  float* g     = ws + OFF_G;
  float* hs2   = ws + OFF_HS2;
  float* gu    = ws + OFF_GU;
  float* act   = ws + OFF_ACT;
  float* h2    = ws + OFF_H2;
  float* mup   = ws + OFF_MUP;

  mup_kernel<<<17, 256, 0, stream>>>(mup);
  // h2 = residual copy; hs_ln = rms(hidden)*w_in_ln
  rms_kernel<<<T_, 256, 0, stream>>>(hidden, w_in_ln, hs_ln, h2);

  // attention branch
  gemm_kernel<<<dim3(16, 24), 256, 0, stream>>>(hs_ln, qkv_w, qkv, nullptr, nullptr,
                                                QKV_N, HID, QKV_N, 1.2f);       // ATTN_IN
  rope_kernel<<<T_, 256, 0, stream>>>(qkv, positions, q, k, v);
  attn_kernel<<<dim3(L_ / 8, NH, B_), 256, 0, stream>>>(q, k, v, attn);
  gemm_kernel<<<dim3(16, 16), 256, 0, stream>>>(attn, o_w, h2, h2, nullptr,
                                                HID, HID, HID, 0.8f);           // h2 += ATTN_OUT*o

  // mamba branch
  gemm_kernel<<<dim3(16, 34), 256, 0, stream>>>(hs_ln, in_proj_w, proj, nullptr, mup,
                                                INPROJ_N, HID, INPROJ_N, 1.1f); // SSM_IN, mup
  dtfix_kernel<<<T_, 256, 0, stream>>>(hs_ln, in_proj_w, proj);                 // exact fp32 dt
  conv_kernel<<<dim3(9, T_), 256, 0, stream>>>(proj, conv_w, conv_b, xbc);
  scan_kernel<<<dim3(MH, B_), 256, 0, stream>>>(xbc, proj, A_log, dt_bias, Dp, y);
  gating_kernel<<<T_, 256, 0, stream>>>(y, proj, ssm_norm_w, g);
  gemm_kernel<<<dim3(16, 16), 256, 0, stream>>>(g, out_proj_w, h2, h2, nullptr,
                                                HID, HID, HID, 0.9f);           // h2 += SSM_OUT*op

  // MLP
  rms_kernel<<<T_, 256, 0, stream>>>(h2, w_pre_ff_ln, hs2, nullptr);
  gemm_kernel<<<dim3(16, 128), 256, 0, stream>>>(hs2, gate_up_w, gu, nullptr, nullptr,
                                                 2 * INTER, HID, 2 * INTER, 1.0f);
  act_kernel<<<dim3(32, T_), 256, 0, stream>>>(gu, act);
  gemm_kernel<<<dim3(16, 16), 256, 0, stream>>>(act, down_w, outp, h2, nullptr,
                                                HID, INTER, HID, 0.8f);         // DOWN_MULT + residual
}

// Round 2
// 2408.027 us; speedup vs baseline: 2.1175x; 2.1175x over previous
//
#include <hip/hip_runtime.h>
#include <hip/hip_bf16.h>
#include <math.h>

// ---------------- problem constants ----------------
#define B_      2
#define L_      1024
#define HID     2048
#define T_      (B_*L_)      // 2048 tokens
#define NH      32
#define HD      64
#define NKV     8
#define INTER   8192
#define DSSM    2048
#define MH      32
#define MP      64
#define MS      64
#define MK      4
#define CONV_DIM 2176
#define QKV_N   3072
#define INPROJ_N 4256

typedef __bf16 bf16x8 __attribute__((ext_vector_type(8)));
typedef __bf16 bf16x4 __attribute__((ext_vector_type(4)));
typedef float  floatx4 __attribute__((ext_vector_type(4)));

// ---------------- workspace layout (float elements) ----------------
static const size_t OFF_HSLN = 0;            // 4194304  (B,L,HID) rms'd input
static const size_t OFF_QKV  = 4194304;      // 6291456
static const size_t OFF_Q    = 10485760;     // 4194304
static const size_t OFF_K    = 14680064;     // 1048576
static const size_t OFF_V    = 15728640;     // 1048576
static const size_t OFF_ATTN = 16777216;     // 4194304  attention out (pre o-proj)
static const size_t OFF_PROJ = 20971520;     // 8716288  in_proj out
static const size_t OFF_XBC  = 29687808;     // 4456448  conv+silu out
static const size_t OFF_Y    = 34144256;     // 4194304  scan out
static const size_t OFF_G    = 38338560;     // 4194304  gated+rms'd
// phase-2 aliases
static const size_t OFF_HS2  = 0;            // 4194304
static const size_t OFF_GU   = 4194304;      // 33554432
static const size_t OFF_ACT  = 37748864;     // 16777216
static const size_t ARENA_END = 54526080;
static const size_t OFF_H2   = ARENA_END;            // 4194304 residual stream
static const size_t OFF_MUP  = ARENA_END + 4194304;  // 4256

// ---------------- helpers ----------------
__device__ inline float block_sum(float v, float* red) {
#pragma unroll
  for (int o = 32; o > 0; o >>= 1) v += __shfl_down(v, o, 64);
  const int lane = threadIdx.x & 63, wv = threadIdx.x >> 6;
  if (lane == 0) red[wv] = v;
  __syncthreads();
  if (threadIdx.x == 0) red[0] = red[0] + red[1] + red[2] + red[3];
  __syncthreads();
  float r = red[0];
  __syncthreads();
  return r;
}

__device__ inline void cvt8(__bf16* dst, float4 a, float4 b) {
  bf16x8 v;
  v[0] = (__bf16)a.x; v[1] = (__bf16)a.y; v[2] = (__bf16)a.z; v[3] = (__bf16)a.w;
  v[4] = (__bf16)b.x; v[5] = (__bf16)b.y; v[6] = (__bf16)b.z; v[7] = (__bf16)b.w;
  *(bf16x8*)dst = v;
}

__device__ inline bf16x8 pack8(float4 a, float4 b, float scale) {
  bf16x8 v;
  v[0] = (__bf16)(a.x * scale); v[1] = (__bf16)(a.y * scale);
  v[2] = (__bf16)(a.z * scale); v[3] = (__bf16)(a.w * scale);
  v[4] = (__bf16)(b.x * scale); v[5] = (__bf16)(b.y * scale);
  v[6] = (__bf16)(b.z * scale); v[7] = (__bf16)(b.w * scale);
  return v;
}

// ---------------- GEMM: out[m,n] = alpha*colscale[n]*sum_k A[m,k]*W[n,k] + addin[m,n]
#define GTM 128
#define GTN 128
#define GTK 32
#define LDSP 40

__global__ __launch_bounds__(256) void gemm_kernel(
    const float* __restrict__ A, const float* __restrict__ W,
    float* __restrict__ out, const float* __restrict__ addin,
    const float* __restrict__ colscale,
    int N, int K, int ldo, float alpha)
{
  __shared__ __align__(16) __bf16 As[GTM * LDSP];
  __shared__ __align__(16) __bf16 Bs[GTN * LDSP];
  const int tid = threadIdx.x;
  const int m0 = blockIdx.x * GTM;
  const int n0 = blockIdx.y * GTN;
  const int lane = tid & 63;
  const int wave = tid >> 6;
  const int wm = (wave >> 1) * 64;
  const int wn = (wave & 1) * 64;
  const int fr = lane & 15;
  const int fq = lane >> 4;

  const int sr = tid >> 1;
  const int sk = (tid & 1) << 4;
  const float* Ap = A + (size_t)(m0 + sr) * K + sk;
  const int nrow = n0 + sr;
  const float* Wp = W + (size_t)nrow * K + sk;
  const bool nvalid = (nrow < N);

  floatx4 acc[4][4];
#pragma unroll
  for (int i = 0; i < 4; i++)
#pragma unroll
    for (int j = 0; j < 4; j++) acc[i][j] = (floatx4){0.f, 0.f, 0.f, 0.f};

  for (int k0 = 0; k0 < K; k0 += GTK) {
    const float4* ap = (const float4*)(Ap + k0);
    float4 a0 = ap[0], a1 = ap[1], a2 = ap[2], a3 = ap[3];
    float4 b0, b1, b2, b3;
    if (nvalid) {
      const float4* wp = (const float4*)(Wp + k0);
      b0 = wp[0]; b1 = wp[1]; b2 = wp[2]; b3 = wp[3];
    } else {
      b0 = b1 = b2 = b3 = make_float4(0.f, 0.f, 0.f, 0.f);
    }
    cvt8(&As[sr * LDSP + sk], a0, a1);
    cvt8(&As[sr * LDSP + sk + 8], a2, a3);
    cvt8(&Bs[sr * LDSP + sk], b0, b1);
    cvt8(&Bs[sr * LDSP + sk + 8], b2, b3);
    __syncthreads();

    bf16x8 aF[4], bF[4];
#pragma unroll
    for (int i = 0; i < 4; i++)
      aF[i] = *(const bf16x8*)&As[(wm + i * 16 + fr) * LDSP + fq * 8];
#pragma unroll
    for (int j = 0; j < 4; j++)
      bF[j] = *(const bf16x8*)&Bs[(wn + j * 16 + fr) * LDSP + fq * 8];
#pragma unroll
    for (int i = 0; i < 4; i++)
#pragma unroll
      for (int j = 0; j < 4; j++)
        acc[i][j] = __builtin_amdgcn_mfma_f32_16x16x32_bf16(aF[i], bF[j], acc[i][j], 0, 0, 0);
    __syncthreads();
  }

#pragma unroll
  for (int i = 0; i < 4; i++) {
#pragma unroll
    for (int r = 0; r < 4; r++) {
      const int m = m0 + wm + i * 16 + fq * 4 + r;
      float* orow = out + (size_t)m * ldo;
      const float* arow = addin ? (addin + (size_t)m * ldo) : nullptr;
#pragma unroll
      for (int j = 0; j < 4; j++) {
        const int n = n0 + wn + j * 16 + fr;
        if (n < N) {
          float vv = acc[i][j][r] * alpha;
          if (colscale) vv *= colscale[n];
          if (arow) vv += arow[n];
          orow[n] = vv;
        }
      }
    }
  }
}

// ---------------- RMSNorm ----------------
__global__ __launch_bounds__(256) void rms_kernel(
    const float* __restrict__ in, const float* __restrict__ w,
    float* __restrict__ outp, float* __restrict__ copy)
{
  __shared__ float buf[HID];
  __shared__ float red[8];
  const int tid = threadIdx.x;
  const size_t t = blockIdx.x;
  const float* row = in + t * HID;
  float ss = 0.f;
  for (int i = tid; i < HID; i += 256) { float x = row[i]; buf[i] = x; ss += x * x; }
  float tot = block_sum(ss, red);
  float inv = rsqrtf(tot / (float)HID + 1e-5f);
  for (int i = tid; i < HID; i += 256) {
    float x = buf[i];
    outp[t * HID + i] = x * inv * w[i];
    if (copy) copy[t * HID + i] = x;
  }
}

// ---------------- mup column-scale vector ----------------
__global__ void mup_kernel(float* __restrict__ mup) {
  int i = blockIdx.x * 256 + threadIdx.x;
  if (i >= INPROJ_N) return;
  float v = (i < DSSM) ? 1.0f
          : (i < 2 * DSSM) ? 0.9f
          : (i < 2 * DSSM + MS) ? 0.8f
          : (i < 2 * DSSM + 2 * MS) ? 1.1f
          : 1.2f;
  mup[i] = v;
}

// ---------------- RoPE + split qkv ----------------
__global__ __launch_bounds__(256) void rope_kernel(
    const float* __restrict__ qkv, const int* __restrict__ positions,
    float* __restrict__ q, float* __restrict__ k, float* __restrict__ v)
{
  __shared__ float inv_s[32];
  const int tid = threadIdx.x;
  const size_t t = blockIdx.x;
  const int l = (int)(t & (L_ - 1));
  if (tid < 32) inv_s[tid] = powf(1.0e11f, -(float)(2 * tid) / 64.f);
  __syncthreads();
  const float pos = (float)positions[l];
  const float* src = qkv + t * QKV_N;
  for (int idx = tid; idx < 1536; idx += 256) {
    int head = idx >> 5, hd = idx & 31;
    if (head < 32) {
      float ang = pos * inv_s[hd];
      float c = cosf(ang), sn = sinf(ang);
      float x1 = src[head * 64 + hd], x2 = src[head * 64 + 32 + hd];
      float* dst = q + (t * NH + head) * HD;
      dst[hd] = x1 * c - x2 * sn;
      dst[hd + 32] = x2 * c + x1 * sn;
    } else if (head < 40) {
      int kk = head - 32;
      float ang = pos * inv_s[hd];
      float c = cosf(ang), sn = sinf(ang);
      float x1 = src[2048 + kk * 64 + hd] * 0.7f;
      float x2 = src[2048 + kk * 64 + 32 + hd] * 0.7f;
      float* dst = k + (t * NKV + kk) * HD;
      dst[hd] = x1 * c - x2 * sn;
      dst[hd + 32] = x2 * c + x1 * sn;
    } else {
      int vv = head - 40;
      float* dst = v + (t * NKV + vv) * HD;
      dst[hd] = src[2560 + vv * 64 + hd];
      dst[hd + 32] = src[2560 + vv * 64 + 32 + hd];
    }
  }
}

// ---------------- flash attention, bf16 MFMA, 64-query tile per block ----------------
// grid: (L_/64, NH, B_). Online softmax in registers (shfl over 16-lane row groups).
// P C-layout -> A-layout via per-wave LDS round-trip; V staged transposed in LDS.
__global__ __launch_bounds__(256) void fattn_kernel(
    const float* __restrict__ q, const float* __restrict__ k,
    const float* __restrict__ v, float* __restrict__ out)
{
  __shared__ __align__(16) __bf16 Vt[64][72];      // [dim][key]
  __shared__ __align__(16) __bf16 Ps[4][16][72];   // per-wave P strip [q16][key]
  const int tid = threadIdx.x;
  const int wave = tid >> 6, lane = tid & 63;
  const int fr = lane & 15, fq = lane >> 4;
  const int qt = (int)(gridDim.x - 1) - blockIdx.x;   // big tiles dispatch first
  const int h = blockIdx.y, b = blockIdx.z, g = h >> 2;
  const int l0 = qt * 64;

  // Q fragments (x 1/sqrt(HD) folded in)
  bf16x8 qf[2];
  {
    const int qrow = l0 + wave * 16 + fr;
    const float* qp = q + (((size_t)(b * L_ + qrow)) * NH + h) * HD;
#pragma unroll
    for (int s = 0; s < 2; s++) {
      float4 x0 = *(const float4*)&qp[s * 32 + fq * 8];
      float4 x1 = *(const float4*)&qp[s * 32 + fq * 8 + 4];
      qf[s] = pack8(x0, x1, 0.125f);
    }
  }

  floatx4 O[4];
  float m_run[4], l_run[4];
#pragma unroll
  for (int i = 0; i < 4; i++) { O[i] = (floatx4){0.f,0.f,0.f,0.f}; m_run[i] = -3.0e38f; l_run[i] = 0.f; }

  for (int kt = 0; kt <= qt; kt++) {
    __syncthreads();   // protect Vt from previous iteration's readers
    // stage V transposed: lane = dim (coalesced global), 4 keys per pass
#pragma unroll
    for (int pp = 0; pp < 4; pp++) {
      const int kb = pp * 4 + (tid >> 6);   // key block 0..15
      bf16x4 pk;
#pragma unroll
      for (int c = 0; c < 4; c++) {
        float vv = v[(((size_t)(b * L_ + kt * 64 + kb * 4 + c)) * NKV + g) * HD + lane];
        pk[c] = (__bf16)vv;
      }
      *(bf16x4*)&Vt[lane][kb * 4] = pk;
    }

    // S = Q K^T  (wave strip: 16 queries x 64 keys)
    floatx4 S[4];
#pragma unroll
    for (int j = 0; j < 4; j++) {
      const float* kp = k + (((size_t)(b * L_ + kt * 64 + j * 16 + fr)) * NKV + g) * HD;
      floatx4 sa = (floatx4){0.f,0.f,0.f,0.f};
#pragma unroll
      for (int s = 0; s < 2; s++) {
        float4 x0 = *(const float4*)&kp[s * 32 + fq * 8];
        float4 x1 = *(const float4*)&kp[s * 32 + fq * 8 + 4];
        bf16x8 kf = pack8(x0, x1, 1.0f);
        sa = __builtin_amdgcn_mfma_f32_16x16x32_bf16(qf[s], kf, sa, 0, 0, 0);
      }
      S[j] = sa;
    }

    // causal mask (only on the diagonal tile)
    if (kt == qt) {
      const int qbase = wave * 16 + fq * 4;   // within tile; keys same 64-span
#pragma unroll
      for (int j = 0; j < 4; j++)
#pragma unroll
        for (int r = 0; r < 4; r++)
          if (j * 16 + fr > qbase + r) S[j][r] = -1.0e30f;
    }

    // online softmax (rows = fq*4+r; reduce across the 16 fr-lanes)
    float rm[4], alpha[4], rsum[4];
#pragma unroll
    for (int r = 0; r < 4; r++)
      rm[r] = fmaxf(fmaxf(S[0][r], S[1][r]), fmaxf(S[2][r], S[3][r]));
#pragma unroll
    for (int msk = 1; msk <= 8; msk <<= 1)
#pragma unroll
      for (int r = 0; r < 4; r++) rm[r] = fmaxf(rm[r], __shfl_xor(rm[r], msk, 64));
#pragma unroll
    for (int r = 0; r < 4; r++) {
      float mnew = fmaxf(m_run[r], rm[r]);
      alpha[r] = __expf(m_run[r] - mnew);
      m_run[r] = mnew;
    }
#pragma unroll
    for (int j = 0; j < 4; j++)
#pragma unroll
      for (int r = 0; r < 4; r++) S[j][r] = __expf(S[j][r] - m_run[r]);
#pragma unroll
    for (int r = 0; r < 4; r++)
      rsum[r] = S[0][r] + S[1][r] + S[2][r] + S[3][r];
#pragma unroll
    for (int msk = 1; msk <= 8; msk <<= 1)
#pragma unroll
      for (int r = 0; r < 4; r++) rsum[r] += __shfl_xor(rsum[r], msk, 64);
#pragma unroll
    for (int r = 0; r < 4; r++) l_run[r] = l_run[r] * alpha[r] + rsum[r];
#pragma unroll
    for (int d4 = 0; d4 < 4; d4++)
#pragma unroll
      for (int r = 0; r < 4; r++) O[d4][r] *= alpha[r];

    // P: C-layout -> LDS (per-wave region)
#pragma unroll
    for (int j = 0; j < 4; j++)
#pragma unroll
      for (int r = 0; r < 4; r++)
        Ps[wave][fq * 4 + r][j * 16 + fr] = (__bf16)S[j][r];

    __syncthreads();   // Vt staged; Ps visible (same-wave anyway)

    // O += P V
#pragma unroll
    for (int s = 0; s < 2; s++) {
      bf16x8 pf = *(const bf16x8*)&Ps[wave][fr][s * 32 + fq * 8];
#pragma unroll
      for (int d4 = 0; d4 < 4; d4++) {
        bf16x8 vf = *(const bf16x8*)&Vt[d4 * 16 + fr][s * 32 + fq * 8];
        O[d4] = __builtin_amdgcn_mfma_f32_16x16x32_bf16(pf, vf, O[d4], 0, 0, 0);
      }
    }
  }

  // epilogue
  float rl[4];
#pragma unroll
  for (int r = 0; r < 4; r++) rl[r] = 1.f / l_run[r];
#pragma unroll
  for (int d4 = 0; d4 < 4; d4++)
#pragma unroll
    for (int r = 0; r < 4; r++) {
      const int qg = l0 + wave * 16 + fq * 4 + r;
      out[((size_t)(b * L_ + qg)) * HID + h * 64 + d4 * 16 + fr] = O[d4][r] * rl[r];
    }
}

// ---------------- exact-fp32 recompute of the 32 dt columns of in_proj ----------------
__global__ __launch_bounds__(256) void dtfix_kernel(
    const float* __restrict__ hs_ln, const float* __restrict__ w, float* __restrict__ proj)
{
  const size_t t = blockIdx.x;
  const int tid = threadIdx.x;
  const int o = tid >> 3, part = tid & 7;
  const float* a = hs_ln + t * HID;
  const float* wr = w + (size_t)(INPROJ_N - MH + o) * HID;
  float s = 0.f;
  for (int kk = part * 4; kk < HID; kk += 32) {
    const float4 av = *(const float4*)&a[kk];
    const float4 wv = *(const float4*)&wr[kk];
    s += av.x * wv.x + av.y * wv.y + av.z * wv.z + av.w * wv.w;
  }
  s += __shfl_xor(s, 1);
  s += __shfl_xor(s, 2);
  s += __shfl_xor(s, 4);
  if (part == 0) proj[t * INPROJ_N + (INPROJ_N - MH) + o] = s * 1.32f; // SSM_IN*mup_dt
}

// ---------------- depthwise causal conv (MK=4) + bias + silu ----------------
__global__ __launch_bounds__(256) void conv_kernel(
    const float* __restrict__ proj, const float* __restrict__ cw,
    const float* __restrict__ cb, float* __restrict__ xbc)
{
  const int c = blockIdx.x * 256 + threadIdx.x;
  if (c >= CONV_DIM) return;
  const int t = blockIdx.y;
  const int l = t & (L_ - 1);
  float acc = cb[c];
#pragma unroll
  for (int kk = 0; kk < MK; kk++) {
    int lp = l - (MK - 1) + kk;
    if (lp >= 0)
      acc += proj[((size_t)(t - (MK - 1) + kk)) * INPROJ_N + DSSM + c] * cw[c * MK + kk];
  }
  xbc[(size_t)t * CONV_DIM + c] = acc / (1.f + __expf(-acc));
}

// ---------------- Mamba2 selective scan: one block per (h, b, p-half), prefetched ----------------
__global__ __launch_bounds__(256) void scan_kernel(
    const float* __restrict__ xbc, const float* __restrict__ proj,
    const float* __restrict__ A_log, const float* __restrict__ dt_bias,
    const float* __restrict__ Dp, float* __restrict__ y)
{
  // grid (MH, B_, 2); thread: p = ph*32 + tid>>3, s-chunk j = tid&7 (8 states each)
  const int tid = threadIdx.x;
  const int h = blockIdx.x, b = blockIdx.y, ph = blockIdx.z;
  const int p = (ph << 5) + (tid >> 3);
  const int j = tid & 7, si = j << 3;
  const float Ah = -expf(A_log[h]);
  const float dtb = dt_bias[h], Dh = Dp[h];
  __shared__ float xs[32], Bs[64], Cs[64];
  __shared__ float dts_s;

  int loff = -1; float* ldst = nullptr;
  if (tid < 32)       { loff = h * 64 + (ph << 5) + tid; ldst = &xs[tid]; }
  else if (tid < 96)  { loff = DSSM + (tid - 32);        ldst = &Bs[tid - 32]; }
  else if (tid < 160) { loff = DSSM + MS + (tid - 96);   ldst = &Cs[tid - 96]; }
  const bool isdt = (tid == 160);

  float pre = 0.f;
  if (loff >= 0)  pre = xbc[((size_t)b * L_) * CONV_DIM + loff];
  else if (isdt)  pre = proj[((size_t)b * L_) * INPROJ_N + (INPROJ_N - MH) + h];

  float st[8];
#pragma unroll
  for (int i = 0; i < 8; i++) st[i] = 0.f;

  for (int l = 0; l < L_; l++) {
    if (loff >= 0) *ldst = pre;
    else if (isdt) dts_s = pre;
    __syncthreads();
    if (l + 1 < L_) {   // prefetch next step while computing this one
      const size_t base = (size_t)b * L_ + (l + 1);
      if (loff >= 0)  pre = xbc[base * CONV_DIM + loff];
      else if (isdt)  pre = proj[base * INPROJ_N + (INPROJ_N - MH) + h];
    }
    float dtv = dts_s + dtb;
    dtv = (dtv > 20.f) ? dtv : log1pf(expf(dtv));
    float dA = expf(dtv * Ah);
    float xv = xs[tid >> 3];
    float dtx = dtv * xv;
    float ys = 0.f;
#pragma unroll
    for (int i = 0; i < 8; i++) {
      st[i] = st[i] * dA + dtx * Bs[si + i];
      ys += st[i] * Cs[si + i];
    }
    ys += __shfl_xor(ys, 1, 64);
    ys += __shfl_xor(ys, 2, 64);
    ys += __shfl_xor(ys, 4, 64);
    if (j == 0) y[((size_t)b * L_ + l) * DSSM + h * 64 + p] = ys + Dh * xv;
    __syncthreads();
  }
}

// ---------------- gating (y * silu(z)) + RMSNorm ----------------
__global__ __launch_bounds__(256) void gating_kernel(
    const float* __restrict__ y, const float* __restrict__ proj,
    const float* __restrict__ nw, float* __restrict__ g)
{
  __shared__ float buf[DSSM];
  __shared__ float red[8];
  const int tid = threadIdx.x;
  const size_t t = blockIdx.x;
  float ss = 0.f;
  for (int i = tid; i < DSSM; i += 256) {
    float zv = proj[t * INPROJ_N + i];
    float yv = y[t * DSSM + i];
    float gv = yv * zv / (1.f + __expf(-zv));
    buf[i] = gv;
    ss += gv * gv;
  }
  float tot = block_sum(ss, red);
  float inv = rsqrtf(tot / (float)DSSM + 1e-5f);
  for (int i = tid; i < DSSM; i += 256) g[t * DSSM + i] = buf[i] * inv * nw[i];
}

// ---------------- SwiGLU activation ----------------
__global__ __launch_bounds__(256) void act_kernel(
    const float* __restrict__ gu, float* __restrict__ act)
{
  const int i = blockIdx.x * 256 + threadIdx.x;
  const size_t t = blockIdx.y;
  float gt = gu[t * (2 * INTER) + i] * 0.9f;
  float up = gu[t * (2 * INTER) + INTER + i];
  act[t * INTER + i] = gt / (1.f + __expf(-gt)) * up;
}

// ---------------- launcher ----------------
extern "C" void kernel_launch(void* const* d_in, const int* in_sizes, int n_in,
                              void* d_out, int out_size, void* d_ws, size_t ws_size,
                              hipStream_t stream)
{
  const float* hidden      = (const float*)d_in[0];
  const int*   positions   = (const int*)d_in[1];
  const float* w_in_ln     = (const float*)d_in[2];
  const float* qkv_w       = (const float*)d_in[3];
  const float* o_w         = (const float*)d_in[4];
  const float* in_proj_w   = (const float*)d_in[5];
  const float* conv_w      = (const float*)d_in[6];
  const float* conv_b      = (const float*)d_in[7];
  const float* A_log       = (const float*)d_in[8];
  const float* dt_bias     = (const float*)d_in[9];
  const float* Dp          = (const float*)d_in[10];
  const float* ssm_norm_w  = (const float*)d_in[11];
  const float* out_proj_w  = (const float*)d_in[12];
  const float* w_pre_ff_ln = (const float*)d_in[13];
  const float* gate_up_w   = (const float*)d_in[14];
  const float* down_w      = (const float*)d_in[15];
  (void)in_sizes; (void)n_in; (void)out_size; (void)ws_size;

  float* ws   = (float*)d_ws;
  float* outp = (float*)d_out;

  float* hs_ln = ws + OFF_HSLN;
  float* qkv   = ws + OFF_QKV;
  float* q     = ws + OFF_Q;
  float* k     = ws + OFF_K;
  float* v     = ws + OFF_V;
  float* attn  = ws + OFF_ATTN;
  float* proj  = ws + OFF_PROJ;
  float* xbc   = ws + OFF_XBC;
  float* y     = ws + OFF_Y;
  float* g     = ws + OFF_G;
  float* hs2   = ws + OFF_HS2;
  float* gu    = ws + OFF_GU;
  float* act   = ws + OFF_ACT;
  float* h2    = ws + OFF_H2;
  float* mup   = ws + OFF_MUP;

  mup_kernel<<<17, 256, 0, stream>>>(mup);
  rms_kernel<<<T_, 256, 0, stream>>>(hidden, w_in_ln, hs_ln, h2);

  // attention branch
  gemm_kernel<<<dim3(16, 24), 256, 0, stream>>>(hs_ln, qkv_w, qkv, nullptr, nullptr,
                                                QKV_N, HID, QKV_N, 1.2f);
  rope_kernel<<<T_, 256, 0, stream>>>(qkv, positions, q, k, v);
  fattn_kernel<<<dim3(L_ / 64, NH, B_), 256, 0, stream>>>(q, k, v, attn);
  gemm_kernel<<<dim3(16, 16), 256, 0, stream>>>(attn, o_w, h2, h2, nullptr,
                                                HID, HID, HID, 0.8f);

  // mamba branch
  gemm_kernel<<<dim3(16, 34), 256, 0, stream>>>(hs_ln, in_proj_w, proj, nullptr, mup,
                                                INPROJ_N, HID, INPROJ_N, 1.1f);
  dtfix_kernel<<<T_, 256, 0, stream>>>(hs_ln, in_proj_w, proj);
  conv_kernel<<<dim3(9, T_), 256, 0, stream>>>(proj, conv_w, conv_b, xbc);
  scan_kernel<<<dim3(MH, B_, 2), 256, 0, stream>>>(xbc, proj, A_log, dt_bias, Dp, y);
  gating_kernel<<<T_, 256, 0, stream>>>(y, proj, ssm_norm_w, g);
  gemm_kernel<<<dim3(16, 16), 256, 0, stream>>>(g, out_proj_w, h2, h2, nullptr,
                                                HID, HID, HID, 0.9f);

  // MLP
  rms_kernel<<<T_, 256, 0, stream>>>(h2, w_pre_ff_ln, hs2, nullptr);
  gemm_kernel<<<dim3(16, 128), 256, 0, stream>>>(hs2, gate_up_w, gu, nullptr, nullptr,
                                                 2 * INTER, HID, 2 * INTER, 1.0f);
  act_kernel<<<dim3(32, T_), 256, 0, stream>>>(gu, act);
  gemm_kernel<<<dim3(16, 16), 256, 0, stream>>>(act, down_w, outp, h2, nullptr,
                                                HID, INTER, HID, 0.8f);
}

// Round 3
// 1670.724 us; speedup vs baseline: 3.0520x; 1.4413x over previous
//
#include <hip/hip_runtime.h>
#include <hip/hip_bf16.h>
#include <math.h>

// ---------------- problem constants ----------------
#define B_      2
#define L_      1024
#define HID     2048
#define T_      (B_*L_)      // 2048 tokens
#define NH      32
#define HD      64
#define NKV     8
#define INTER   8192
#define DSSM    2048
#define MH      32
#define MP      64
#define MS      64
#define MK      4
#define CONV_DIM 2176
#define QKV_N   3072
#define INPROJ_N 4256
#define CH      16     // scan chunks
#define CL      64     // chunk length

typedef __bf16 bf16x8 __attribute__((ext_vector_type(8)));
typedef __bf16 bf16x4 __attribute__((ext_vector_type(4)));
typedef float  floatx4 __attribute__((ext_vector_type(4)));

// ---------------- workspace layout (float elements) ----------------
static const size_t OFF_HSLN = 0;            // 4194304  (B,L,HID) rms'd input
static const size_t OFF_QKV  = 4194304;      // 6291456
static const size_t OFF_Q    = 10485760;     // 4194304  (aliased by Tbuf after fattn)
static const size_t OFF_K    = 14680064;     // 1048576  (aliased by dec after fattn)
static const size_t OFF_V    = 15728640;     // 1048576  (aliased by lam after fattn)
static const size_t OFF_ATTN = 16777216;     // 4194304  attention out (pre o-proj)
static const size_t OFF_PROJ = 20971520;     // 8716288  in_proj out
static const size_t OFF_XBC  = 29687808;     // 4456448  conv+silu out
static const size_t OFF_Y    = 34144256;     // 4194304  scan out
static const size_t OFF_G    = 38338560;     // 4194304  gated+rms'd
// phase-2 aliases
static const size_t OFF_HS2  = 0;            // 4194304
static const size_t OFF_GU   = 4194304;      // 33554432
static const size_t OFF_ACT  = 37748864;     // 16777216
static const size_t ARENA_END = 54526080;
static const size_t OFF_H2   = ARENA_END;            // 4194304 residual stream
static const size_t OFF_MUP  = ARENA_END + 4194304;  // 4256

// ---------------- helpers ----------------
__device__ inline float block_sum(float v, float* red) {
#pragma unroll
  for (int o = 32; o > 0; o >>= 1) v += __shfl_down(v, o, 64);
  const int lane = threadIdx.x & 63, wv = threadIdx.x >> 6;
  if (lane == 0) red[wv] = v;
  __syncthreads();
  if (threadIdx.x == 0) red[0] = red[0] + red[1] + red[2] + red[3];
  __syncthreads();
  float r = red[0];
  __syncthreads();
  return r;
}

__device__ inline void cvt8(__bf16* dst, float4 a, float4 b) {
  bf16x8 v;
  v[0] = (__bf16)a.x; v[1] = (__bf16)a.y; v[2] = (__bf16)a.z; v[3] = (__bf16)a.w;
  v[4] = (__bf16)b.x; v[5] = (__bf16)b.y; v[6] = (__bf16)b.z; v[7] = (__bf16)b.w;
  *(bf16x8*)dst = v;
}

__device__ inline bf16x8 pack8(float4 a, float4 b, float scale) {
  bf16x8 v;
  v[0] = (__bf16)(a.x * scale); v[1] = (__bf16)(a.y * scale);
  v[2] = (__bf16)(a.z * scale); v[3] = (__bf16)(a.w * scale);
  v[4] = (__bf16)(b.x * scale); v[5] = (__bf16)(b.y * scale);
  v[6] = (__bf16)(b.z * scale); v[7] = (__bf16)(b.w * scale);
  return v;
}

// ---------------- GEMM: out[m,n] = alpha*colscale[n]*sum_k A[m,k]*W[n,k] + addin[m,n]
#define GTM 128
#define GTN 128
#define GTK 32
#define LDSP 40

__global__ __launch_bounds__(256) void gemm_kernel(
    const float* __restrict__ A, const float* __restrict__ W,
    float* __restrict__ out, const float* __restrict__ addin,
    const float* __restrict__ colscale,
    int N, int K, int ldo, float alpha)
{
  __shared__ __align__(16) __bf16 As[GTM * LDSP];
  __shared__ __align__(16) __bf16 Bs[GTN * LDSP];
  const int tid = threadIdx.x;
  const int m0 = blockIdx.x * GTM;
  const int n0 = blockIdx.y * GTN;
  const int lane = tid & 63;
  const int wave = tid >> 6;
  const int wm = (wave >> 1) * 64;
  const int wn = (wave & 1) * 64;
  const int fr = lane & 15;
  const int fq = lane >> 4;

  const int sr = tid >> 1;
  const int sk = (tid & 1) << 4;
  const float* Ap = A + (size_t)(m0 + sr) * K + sk;
  const int nrow = n0 + sr;
  const float* Wp = W + (size_t)nrow * K + sk;
  const bool nvalid = (nrow < N);

  floatx4 acc[4][4];
#pragma unroll
  for (int i = 0; i < 4; i++)
#pragma unroll
    for (int j = 0; j < 4; j++) acc[i][j] = (floatx4){0.f, 0.f, 0.f, 0.f};

  for (int k0 = 0; k0 < K; k0 += GTK) {
    const float4* ap = (const float4*)(Ap + k0);
    float4 a0 = ap[0], a1 = ap[1], a2 = ap[2], a3 = ap[3];
    float4 b0, b1, b2, b3;
    if (nvalid) {
      const float4* wp = (const float4*)(Wp + k0);
      b0 = wp[0]; b1 = wp[1]; b2 = wp[2]; b3 = wp[3];
    } else {
      b0 = b1 = b2 = b3 = make_float4(0.f, 0.f, 0.f, 0.f);
    }
    cvt8(&As[sr * LDSP + sk], a0, a1);
    cvt8(&As[sr * LDSP + sk + 8], a2, a3);
    cvt8(&Bs[sr * LDSP + sk], b0, b1);
    cvt8(&Bs[sr * LDSP + sk + 8], b2, b3);
    __syncthreads();

    bf16x8 aF[4], bF[4];
#pragma unroll
    for (int i = 0; i < 4; i++)
      aF[i] = *(const bf16x8*)&As[(wm + i * 16 + fr) * LDSP + fq * 8];
#pragma unroll
    for (int j = 0; j < 4; j++)
      bF[j] = *(const bf16x8*)&Bs[(wn + j * 16 + fr) * LDSP + fq * 8];
#pragma unroll
    for (int i = 0; i < 4; i++)
#pragma unroll
      for (int j = 0; j < 4; j++)
        acc[i][j] = __builtin_amdgcn_mfma_f32_16x16x32_bf16(aF[i], bF[j], acc[i][j], 0, 0, 0);
    __syncthreads();
  }

#pragma unroll
  for (int i = 0; i < 4; i++) {
#pragma unroll
    for (int r = 0; r < 4; r++) {
      const int m = m0 + wm + i * 16 + fq * 4 + r;
      float* orow = out + (size_t)m * ldo;
      const float* arow = addin ? (addin + (size_t)m * ldo) : nullptr;
#pragma unroll
      for (int j = 0; j < 4; j++) {
        const int n = n0 + wn + j * 16 + fr;
        if (n < N) {
          float vv = acc[i][j][r] * alpha;
          if (colscale) vv *= colscale[n];
          if (arow) vv += arow[n];
          orow[n] = vv;
        }
      }
    }
  }
}

// ---------------- RMSNorm ----------------
__global__ __launch_bounds__(256) void rms_kernel(
    const float* __restrict__ in, const float* __restrict__ w,
    float* __restrict__ outp, float* __restrict__ copy)
{
  __shared__ float buf[HID];
  __shared__ float red[8];
  const int tid = threadIdx.x;
  const size_t t = blockIdx.x;
  const float* row = in + t * HID;
  float ss = 0.f;
  for (int i = tid; i < HID; i += 256) { float x = row[i]; buf[i] = x; ss += x * x; }
  float tot = block_sum(ss, red);
  float inv = rsqrtf(tot / (float)HID + 1e-5f);
  for (int i = tid; i < HID; i += 256) {
    float x = buf[i];
    outp[t * HID + i] = x * inv * w[i];
    if (copy) copy[t * HID + i] = x;
  }
}

// ---------------- mup column-scale vector ----------------
__global__ void mup_kernel(float* __restrict__ mup) {
  int i = blockIdx.x * 256 + threadIdx.x;
  if (i >= INPROJ_N) return;
  float v = (i < DSSM) ? 1.0f
          : (i < 2 * DSSM) ? 0.9f
          : (i < 2 * DSSM + MS) ? 0.8f
          : (i < 2 * DSSM + 2 * MS) ? 1.1f
          : 1.2f;
  mup[i] = v;
}

// ---------------- RoPE + split qkv ----------------
__global__ __launch_bounds__(256) void rope_kernel(
    const float* __restrict__ qkv, const int* __restrict__ positions,
    float* __restrict__ q, float* __restrict__ k, float* __restrict__ v)
{
  __shared__ float inv_s[32];
  const int tid = threadIdx.x;
  const size_t t = blockIdx.x;
  const int l = (int)(t & (L_ - 1));
  if (tid < 32) inv_s[tid] = powf(1.0e11f, -(float)(2 * tid) / 64.f);
  __syncthreads();
  const float pos = (float)positions[l];
  const float* src = qkv + t * QKV_N;
  for (int idx = tid; idx < 1536; idx += 256) {
    int head = idx >> 5, hd = idx & 31;
    if (head < 32) {
      float ang = pos * inv_s[hd];
      float c = cosf(ang), sn = sinf(ang);
      float x1 = src[head * 64 + hd], x2 = src[head * 64 + 32 + hd];
      float* dst = q + (t * NH + head) * HD;
      dst[hd] = x1 * c - x2 * sn;
      dst[hd + 32] = x2 * c + x1 * sn;
    } else if (head < 40) {
      int kk = head - 32;
      float ang = pos * inv_s[hd];
      float c = cosf(ang), sn = sinf(ang);
      float x1 = src[2048 + kk * 64 + hd] * 0.7f;
      float x2 = src[2048 + kk * 64 + 32 + hd] * 0.7f;
      float* dst = k + (t * NKV + kk) * HD;
      dst[hd] = x1 * c - x2 * sn;
      dst[hd + 32] = x2 * c + x1 * sn;
    } else {
      int vv = head - 40;
      float* dst = v + (t * NKV + vv) * HD;
      dst[hd] = src[2560 + vv * 64 + hd];
      dst[hd + 32] = src[2560 + vv * 64 + 32 + hd];
    }
  }
}

// ---------------- flash attention, bf16 MFMA, 64-query tile per block ----------------
__global__ __launch_bounds__(256) void fattn_kernel(
    const float* __restrict__ q, const float* __restrict__ k,
    const float* __restrict__ v, float* __restrict__ out)
{
  __shared__ __align__(16) __bf16 Vt[64][72];      // [dim][key]
  __shared__ __align__(16) __bf16 Ps[4][16][72];   // per-wave P strip [q16][key]
  const int tid = threadIdx.x;
  const int wave = tid >> 6, lane = tid & 63;
  const int fr = lane & 15, fq = lane >> 4;
  const int qt = (int)(gridDim.x - 1) - blockIdx.x;   // big tiles dispatch first
  const int h = blockIdx.y, b = blockIdx.z, g = h >> 2;
  const int l0 = qt * 64;

  bf16x8 qf[2];
  {
    const int qrow = l0 + wave * 16 + fr;
    const float* qp = q + (((size_t)(b * L_ + qrow)) * NH + h) * HD;
#pragma unroll
    for (int s = 0; s < 2; s++) {
      float4 x0 = *(const float4*)&qp[s * 32 + fq * 8];
      float4 x1 = *(const float4*)&qp[s * 32 + fq * 8 + 4];
      qf[s] = pack8(x0, x1, 0.125f);
    }
  }

  floatx4 O[4];
  float m_run[4], l_run[4];
#pragma unroll
  for (int i = 0; i < 4; i++) { O[i] = (floatx4){0.f,0.f,0.f,0.f}; m_run[i] = -3.0e38f; l_run[i] = 0.f; }

  for (int kt = 0; kt <= qt; kt++) {
    __syncthreads();
#pragma unroll
    for (int pp = 0; pp < 4; pp++) {
      const int kb = pp * 4 + (tid >> 6);
      bf16x4 pk;
#pragma unroll
      for (int c = 0; c < 4; c++) {
        float vv = v[(((size_t)(b * L_ + kt * 64 + kb * 4 + c)) * NKV + g) * HD + lane];
        pk[c] = (__bf16)vv;
      }
      *(bf16x4*)&Vt[lane][kb * 4] = pk;
    }

    floatx4 S[4];
#pragma unroll
    for (int j = 0; j < 4; j++) {
      const float* kp = k + (((size_t)(b * L_ + kt * 64 + j * 16 + fr)) * NKV + g) * HD;
      floatx4 sa = (floatx4){0.f,0.f,0.f,0.f};
#pragma unroll
      for (int s = 0; s < 2; s++) {
        float4 x0 = *(const float4*)&kp[s * 32 + fq * 8];
        float4 x1 = *(const float4*)&kp[s * 32 + fq * 8 + 4];
        bf16x8 kf = pack8(x0, x1, 1.0f);
        sa = __builtin_amdgcn_mfma_f32_16x16x32_bf16(qf[s], kf, sa, 0, 0, 0);
      }
      S[j] = sa;
    }

    if (kt == qt) {
      const int qbase = wave * 16 + fq * 4;
#pragma unroll
      for (int j = 0; j < 4; j++)
#pragma unroll
        for (int r = 0; r < 4; r++)
          if (j * 16 + fr > qbase + r) S[j][r] = -1.0e30f;
    }

    float rm[4], alpha[4], rsum[4];
#pragma unroll
    for (int r = 0; r < 4; r++)
      rm[r] = fmaxf(fmaxf(S[0][r], S[1][r]), fmaxf(S[2][r], S[3][r]));
#pragma unroll
    for (int msk = 1; msk <= 8; msk <<= 1)
#pragma unroll
      for (int r = 0; r < 4; r++) rm[r] = fmaxf(rm[r], __shfl_xor(rm[r], msk, 64));
#pragma unroll
    for (int r = 0; r < 4; r++) {
      float mnew = fmaxf(m_run[r], rm[r]);
      alpha[r] = __expf(m_run[r] - mnew);
      m_run[r] = mnew;
    }
#pragma unroll
    for (int j = 0; j < 4; j++)
#pragma unroll
      for (int r = 0; r < 4; r++) S[j][r] = __expf(S[j][r] - m_run[r]);
#pragma unroll
    for (int r = 0; r < 4; r++)
      rsum[r] = S[0][r] + S[1][r] + S[2][r] + S[3][r];
#pragma unroll
    for (int msk = 1; msk <= 8; msk <<= 1)
#pragma unroll
      for (int r = 0; r < 4; r++) rsum[r] += __shfl_xor(rsum[r], msk, 64);
#pragma unroll
    for (int r = 0; r < 4; r++) l_run[r] = l_run[r] * alpha[r] + rsum[r];
#pragma unroll
    for (int d4 = 0; d4 < 4; d4++)
#pragma unroll
      for (int r = 0; r < 4; r++) O[d4][r] *= alpha[r];

#pragma unroll
    for (int j = 0; j < 4; j++)
#pragma unroll
      for (int r = 0; r < 4; r++)
        Ps[wave][fq * 4 + r][j * 16 + fr] = (__bf16)S[j][r];

    __syncthreads();

#pragma unroll
    for (int s = 0; s < 2; s++) {
      bf16x8 pf = *(const bf16x8*)&Ps[wave][fr][s * 32 + fq * 8];
#pragma unroll
      for (int d4 = 0; d4 < 4; d4++) {
        bf16x8 vf = *(const bf16x8*)&Vt[d4 * 16 + fr][s * 32 + fq * 8];
        O[d4] = __builtin_amdgcn_mfma_f32_16x16x32_bf16(pf, vf, O[d4], 0, 0, 0);
      }
    }
  }

  float rl[4];
#pragma unroll
  for (int r = 0; r < 4; r++) rl[r] = 1.f / l_run[r];
#pragma unroll
  for (int d4 = 0; d4 < 4; d4++)
#pragma unroll
    for (int r = 0; r < 4; r++) {
      const int qg = l0 + wave * 16 + fq * 4 + r;
      out[((size_t)(b * L_ + qg)) * HID + h * 64 + d4 * 16 + fr] = O[d4][r] * rl[r];
    }
}

// ---------------- exact-fp32 recompute of the 32 dt columns of in_proj ----------------
__global__ __launch_bounds__(256) void dtfix_kernel(
    const float* __restrict__ hs_ln, const float* __restrict__ w, float* __restrict__ proj)
{
  const size_t t = blockIdx.x;
  const int tid = threadIdx.x;
  const int o = tid >> 3, part = tid & 7;
  const float* a = hs_ln + t * HID;
  const float* wr = w + (size_t)(INPROJ_N - MH + o) * HID;
  float s = 0.f;
  for (int kk = part * 4; kk < HID; kk += 32) {
    const float4 av = *(const float4*)&a[kk];
    const float4 wv = *(const float4*)&wr[kk];
    s += av.x * wv.x + av.y * wv.y + av.z * wv.z + av.w * wv.w;
  }
  s += __shfl_xor(s, 1);
  s += __shfl_xor(s, 2);
  s += __shfl_xor(s, 4);
  if (part == 0) proj[t * INPROJ_N + (INPROJ_N - MH) + o] = s * 1.32f; // SSM_IN*mup_dt
}

// ---------------- depthwise causal conv (MK=4) + bias + silu ----------------
__global__ __launch_bounds__(256) void conv_kernel(
    const float* __restrict__ proj, const float* __restrict__ cw,
    const float* __restrict__ cb, float* __restrict__ xbc)
{
  const int c = blockIdx.x * 256 + threadIdx.x;
  if (c >= CONV_DIM) return;
  const int t = blockIdx.y;
  const int l = t & (L_ - 1);
  float acc = cb[c];
#pragma unroll
  for (int kk = 0; kk < MK; kk++) {
    int lp = l - (MK - 1) + kk;
    if (lp >= 0)
      acc += proj[((size_t)(t - (MK - 1) + kk)) * INPROJ_N + DSSM + c] * cw[c * MK + kk];
  }
  xbc[(size_t)t * CONV_DIM + c] = acc / (1.f + __expf(-acc));
}

// ---------------- chunked Mamba2 scan, stage A: intra-chunk (parallel, MFMA) -------
// grid (CH, MH, B_). Per chunk: M=(C B^T)*decaymask -> Y_intra = M X + D x;
// T[p][s] = sum_l x[l,p] * (e^{cumend-cum_l} dt_l) B[l,s];  lam = e^{cumend}; dec_l = e^{cum_l}
__global__ __launch_bounds__(256) void scanA_kernel(
    const float* __restrict__ xbc, const float* __restrict__ proj,
    const float* __restrict__ A_log, const float* __restrict__ dt_bias,
    const float* __restrict__ Dp,
    float* __restrict__ y, float* __restrict__ Tbuf,
    float* __restrict__ lam, float* __restrict__ dec)
{
  __shared__ __align__(16) __bf16 xT[64][72];    // [p][l]
  __shared__ __align__(16) __bf16 BTw[64][72];   // [s][l] (scaled)
  __shared__ __align__(16) __bf16 Braw[64][72];  // [l][s]
  __shared__ __align__(16) __bf16 Craw[64][72];  // [l][s]
  __shared__ __align__(16) __bf16 Ps[4][16][72]; // per-wave M strip
  __shared__ float dt_s[64], cum_s[64];

  const int tid = threadIdx.x;
  const int lane = tid & 63, wave = tid >> 6;
  const int fr = lane & 15, fq = lane >> 4;
  const int c = blockIdx.x, h = blockIdx.y, b = blockIdx.z;
  const int t0 = b * L_ + c * CL;
  const float Ah = -expf(A_log[h]);
  const float dtb = dt_bias[h], Dh = Dp[h];

  // dt + inclusive cumsum of a_l = dt_l*A (wave 0, fp32 exact)
  if (wave == 0) {
    float draw = proj[(size_t)(t0 + lane) * INPROJ_N + (INPROJ_N - MH) + h];
    float dtv = draw + dtb;
    dtv = (dtv > 20.f) ? dtv : log1pf(__expf(dtv));
    float cs = dtv * Ah;
#pragma unroll
    for (int d = 1; d < 64; d <<= 1) {
      float nv = __shfl_up(cs, d, 64);
      if (lane >= d) cs += nv;
    }
    dt_s[lane] = dtv;
    cum_s[lane] = cs;
  }

  // stage x (transposed), Braw, Craw
#pragma unroll
  for (int pass = 0; pass < 4; pass++) {
    const int l = pass * 16 + (tid >> 4);
    const int s4 = (tid & 15) * 4;
    const float* rowp = xbc + (size_t)(t0 + l) * CONV_DIM;
    float4 xv = *(const float4*)&rowp[h * 64 + s4];
    float4 bv = *(const float4*)&rowp[DSSM + s4];
    float4 cv = *(const float4*)&rowp[DSSM + MS + s4];
    xT[s4 + 0][l] = (__bf16)xv.x;
    xT[s4 + 1][l] = (__bf16)xv.y;
    xT[s4 + 2][l] = (__bf16)xv.z;
    xT[s4 + 3][l] = (__bf16)xv.w;
    bf16x4 b4; b4[0]=(__bf16)bv.x; b4[1]=(__bf16)bv.y; b4[2]=(__bf16)bv.z; b4[3]=(__bf16)bv.w;
    *(bf16x4*)&Braw[l][s4] = b4;
    bf16x4 c4; c4[0]=(__bf16)cv.x; c4[1]=(__bf16)cv.y; c4[2]=(__bf16)cv.z; c4[3]=(__bf16)cv.w;
    *(bf16x4*)&Craw[l][s4] = c4;
  }
  __syncthreads();

  // stage BTw = B^T scaled by w_l = e^{cumend - cum_l} * dt_l
  const float cend = cum_s[63];
#pragma unroll
  for (int pass = 0; pass < 4; pass++) {
    const int l = pass * 16 + (tid >> 4);
    const int s4 = (tid & 15) * 4;
    const float wl = __expf(cend - cum_s[l]) * dt_s[l];
    float4 bv = *(const float4*)&xbc[(size_t)(t0 + l) * CONV_DIM + DSSM + s4];
    BTw[s4 + 0][l] = (__bf16)(bv.x * wl);
    BTw[s4 + 1][l] = (__bf16)(bv.y * wl);
    BTw[s4 + 2][l] = (__bf16)(bv.z * wl);
    BTw[s4 + 3][l] = (__bf16)(bv.w * wl);
  }

  // M = C B^T (wave strip: 16 l x 64 m), then mask/scale -> Ps (bf16)
  {
    bf16x8 aF0 = *(const bf16x8*)&Craw[wave * 16 + fr][fq * 8];
    bf16x8 aF1 = *(const bf16x8*)&Craw[wave * 16 + fr][fq * 8 + 32];
#pragma unroll
    for (int j = 0; j < 4; j++) {
      floatx4 s = (floatx4){0.f,0.f,0.f,0.f};
      bf16x8 b0 = *(const bf16x8*)&Braw[j * 16 + fr][fq * 8];
      bf16x8 b1 = *(const bf16x8*)&Braw[j * 16 + fr][fq * 8 + 32];
      s = __builtin_amdgcn_mfma_f32_16x16x32_bf16(aF0, b0, s, 0, 0, 0);
      s = __builtin_amdgcn_mfma_f32_16x16x32_bf16(aF1, b1, s, 0, 0, 0);
      const int m = j * 16 + fr;
      const float dtm = dt_s[m], cmm = cum_s[m];
#pragma unroll
      for (int r = 0; r < 4; r++) {
        const int lR = wave * 16 + fq * 4 + r;
        float f = (m <= lR) ? __expf(cum_s[lR] - cmm) * dtm : 0.f;
        Ps[wave][fq * 4 + r][m] = (__bf16)(s[r] * f);
      }
    }
  }
  __syncthreads();   // BTw staged by all; Ps is same-wave

  // Y_intra = M @ X  (+ D*x), write y
  {
    bf16x8 aF0 = *(const bf16x8*)&Ps[wave][fr][fq * 8];
    bf16x8 aF1 = *(const bf16x8*)&Ps[wave][fr][fq * 8 + 32];
#pragma unroll
    for (int j = 0; j < 4; j++) {
      floatx4 s = (floatx4){0.f,0.f,0.f,0.f};
      bf16x8 b0 = *(const bf16x8*)&xT[j * 16 + fr][fq * 8];
      bf16x8 b1 = *(const bf16x8*)&xT[j * 16 + fr][fq * 8 + 32];
      s = __builtin_amdgcn_mfma_f32_16x16x32_bf16(aF0, b0, s, 0, 0, 0);
      s = __builtin_amdgcn_mfma_f32_16x16x32_bf16(aF1, b1, s, 0, 0, 0);
      const int p = j * 16 + fr;
#pragma unroll
      for (int r = 0; r < 4; r++) {
        const int lR = wave * 16 + fq * 4 + r;
        float xval = (float)xT[p][lR];
        y[(size_t)(t0 + lR) * DSSM + h * 64 + p] = s[r] + Dh * xval;
      }
    }
  }

  // T[p][s] = sum_l xT[p][l] * BTw[s][l]
  {
    float* Tb = Tbuf + ((size_t)((b * MH + h) * CH + c)) * 4096;
    bf16x8 aF0 = *(const bf16x8*)&xT[wave * 16 + fr][fq * 8];
    bf16x8 aF1 = *(const bf16x8*)&xT[wave * 16 + fr][fq * 8 + 32];
#pragma unroll
    for (int j = 0; j < 4; j++) {
      floatx4 s = (floatx4){0.f,0.f,0.f,0.f};
      bf16x8 b0 = *(const bf16x8*)&BTw[j * 16 + fr][fq * 8];
      bf16x8 b1 = *(const bf16x8*)&BTw[j * 16 + fr][fq * 8 + 32];
      s = __builtin_amdgcn_mfma_f32_16x16x32_bf16(aF0, b0, s, 0, 0, 0);
      s = __builtin_amdgcn_mfma_f32_16x16x32_bf16(aF1, b1, s, 0, 0, 0);
#pragma unroll
      for (int r = 0; r < 4; r++)
        Tb[(wave * 16 + fq * 4 + r) * 64 + j * 16 + fr] = s[r];
    }
  }

  if (tid == 0) lam[(b * MH + h) * CH + c] = __expf(cend);
  if (tid >= 64 && tid < 128)
    dec[((size_t)((b * MH + h) * CH + c)) * 64 + (tid - 64)] = __expf(cum_s[tid - 64]);
}

// ---------------- chunked scan, stage B: 16-step inter-chunk state scan + Y_inter --
// grid (MH, B_). State S[p][s] fp32 in LDS; per chunk: y += dec_l * (C_l . S_prev[p,:])
__global__ __launch_bounds__(256) void scanB_kernel(
    const float* __restrict__ xbc, const float* __restrict__ Tbuf,
    const float* __restrict__ lam, const float* __restrict__ dec,
    float* __restrict__ y)
{
  __shared__ __align__(16) float S[64][68];
  __shared__ __align__(16) __bf16 Cc[64][72];
  __shared__ float decl[64];
  const int tid = threadIdx.x;
  const int lane = tid & 63, wave = tid >> 6;
  const int fr = lane & 15, fq = lane >> 4;
  const int h = blockIdx.x, b = blockIdx.y;

  const int sown = tid & 63, pbase = (tid >> 6) * 16;
#pragma unroll
  for (int i = 0; i < 16; i++) S[pbase + i][sown] = 0.f;
  __syncthreads();

  for (int c = 0; c < CH; c++) {
    const int t0 = b * L_ + c * CL;
#pragma unroll
    for (int pass = 0; pass < 4; pass++) {
      const int l = pass * 16 + (tid >> 4);
      const int s4 = (tid & 15) * 4;
      float4 cv = *(const float4*)&xbc[(size_t)(t0 + l) * CONV_DIM + DSSM + MS + s4];
      bf16x4 c4; c4[0]=(__bf16)cv.x; c4[1]=(__bf16)cv.y; c4[2]=(__bf16)cv.z; c4[3]=(__bf16)cv.w;
      *(bf16x4*)&Cc[l][s4] = c4;
    }
    if (tid < 64) decl[tid] = dec[((size_t)((b * MH + h) * CH + c)) * 64 + tid];
    __syncthreads();

    if (c > 0) {
      bf16x8 aF0 = *(const bf16x8*)&Cc[wave * 16 + fr][fq * 8];
      bf16x8 aF1 = *(const bf16x8*)&Cc[wave * 16 + fr][fq * 8 + 32];
#pragma unroll
      for (int j = 0; j < 4; j++) {
        const float* srow = &S[j * 16 + fr][0];
        float4 s0 = *(const float4*)&srow[fq * 8];
        float4 s1 = *(const float4*)&srow[fq * 8 + 4];
        float4 s2 = *(const float4*)&srow[fq * 8 + 32];
        float4 s3 = *(const float4*)&srow[fq * 8 + 36];
        bf16x8 b0 = pack8(s0, s1, 1.f);
        bf16x8 b1 = pack8(s2, s3, 1.f);
        floatx4 acc = (floatx4){0.f,0.f,0.f,0.f};
        acc = __builtin_amdgcn_mfma_f32_16x16x32_bf16(aF0, b0, acc, 0, 0, 0);
        acc = __builtin_amdgcn_mfma_f32_16x16x32_bf16(aF1, b1, acc, 0, 0, 0);
        const int p = j * 16 + fr;
#pragma unroll
        for (int r = 0; r < 4; r++) {
          const int lR = wave * 16 + fq * 4 + r;
          float* yp = &y[(size_t)(t0 + lR) * DSSM + h * 64 + p];
          *yp += decl[lR] * acc[r];
        }
      }
    }
    __syncthreads();   // all S reads done before update

    const float lc = lam[(b * MH + h) * CH + c];
    const float* Tb = Tbuf + ((size_t)((b * MH + h) * CH + c)) * 4096;
#pragma unroll
    for (int i = 0; i < 16; i++) {
      float tv = Tb[(pbase + i) * 64 + sown];
      S[pbase + i][sown] = lc * S[pbase + i][sown] + tv;
    }
    __syncthreads();
  }
}

// ---------------- gating (y * silu(z)) + RMSNorm ----------------
__global__ __launch_bounds__(256) void gating_kernel(
    const float* __restrict__ y, const float* __restrict__ proj,
    const float* __restrict__ nw, float* __restrict__ g)
{
  __shared__ float buf[DSSM];
  __shared__ float red[8];
  const int tid = threadIdx.x;
  const size_t t = blockIdx.x;
  float ss = 0.f;
  for (int i = tid; i < DSSM; i += 256) {
    float zv = proj[t * INPROJ_N + i];
    float yv = y[t * DSSM + i];
    float gv = yv * zv / (1.f + __expf(-zv));
    buf[i] = gv;
    ss += gv * gv;
  }
  float tot = block_sum(ss, red);
  float inv = rsqrtf(tot / (float)DSSM + 1e-5f);
  for (int i = tid; i < DSSM; i += 256) g[t * DSSM + i] = buf[i] * inv * nw[i];
}

// ---------------- SwiGLU activation ----------------
__global__ __launch_bounds__(256) void act_kernel(
    const float* __restrict__ gu, float* __restrict__ act)
{
  const int i = blockIdx.x * 256 + threadIdx.x;
  const size_t t = blockIdx.y;
  float gt = gu[t * (2 * INTER) + i] * 0.9f;
  float up = gu[t * (2 * INTER) + INTER + i];
  act[t * INTER + i] = gt / (1.f + __expf(-gt)) * up;
}

// ---------------- launcher ----------------
extern "C" void kernel_launch(void* const* d_in, const int* in_sizes, int n_in,
                              void* d_out, int out_size, void* d_ws, size_t ws_size,
                              hipStream_t stream)
{
  const float* hidden      = (const float*)d_in[0];
  const int*   positions   = (const int*)d_in[1];
  const float* w_in_ln     = (const float*)d_in[2];
  const float* qkv_w       = (const float*)d_in[3];
  const float* o_w         = (const float*)d_in[4];
  const float* in_proj_w   = (const float*)d_in[5];
  const float* conv_w      = (const float*)d_in[6];
  const float* conv_b      = (const float*)d_in[7];
  const float* A_log       = (const float*)d_in[8];
  const float* dt_bias     = (const float*)d_in[9];
  const float* Dp          = (const float*)d_in[10];
  const float* ssm_norm_w  = (const float*)d_in[11];
  const float* out_proj_w  = (const float*)d_in[12];
  const float* w_pre_ff_ln = (const float*)d_in[13];
  const float* gate_up_w   = (const float*)d_in[14];
  const float* down_w      = (const float*)d_in[15];
  (void)in_sizes; (void)n_in; (void)out_size; (void)ws_size;

  float* ws   = (float*)d_ws;
  float* outp = (float*)d_out;

  float* hs_ln = ws + OFF_HSLN;
  float* qkv   = ws + OFF_QKV;
  float* q     = ws + OFF_Q;
  float* k     = ws + OFF_K;
  float* v     = ws + OFF_V;
  float* attn  = ws + OFF_ATTN;
  float* proj  = ws + OFF_PROJ;
  float* xbc   = ws + OFF_XBC;
  float* y     = ws + OFF_Y;
  float* g     = ws + OFF_G;
  float* hs2   = ws + OFF_HS2;
  float* gu    = ws + OFF_GU;
  float* act   = ws + OFF_ACT;
  float* h2    = ws + OFF_H2;
  float* mup   = ws + OFF_MUP;
  // scan scratch aliases q/k/v (dead after fattn)
  float* Tbuf  = ws + OFF_Q;   // 4,194,304 floats exactly
  float* dec   = ws + OFF_K;   // 65,536 floats
  float* lam   = ws + OFF_V;   // 1,024 floats

  mup_kernel<<<17, 256, 0, stream>>>(mup);
  rms_kernel<<<T_, 256, 0, stream>>>(hidden, w_in_ln, hs_ln, h2);

  // attention branch
  gemm_kernel<<<dim3(16, 24), 256, 0, stream>>>(hs_ln, qkv_w, qkv, nullptr, nullptr,
                                                QKV_N, HID, QKV_N, 1.2f);
  rope_kernel<<<T_, 256, 0, stream>>>(qkv, positions, q, k, v);
  fattn_kernel<<<dim3(L_ / 64, NH, B_), 256, 0, stream>>>(q, k, v, attn);
  gemm_kernel<<<dim3(16, 16), 256, 0, stream>>>(attn, o_w, h2, h2, nullptr,
                                                HID, HID, HID, 0.8f);

  // mamba branch
  gemm_kernel<<<dim3(16, 34), 256, 0, stream>>>(hs_ln, in_proj_w, proj, nullptr, mup,
                                                INPROJ_N, HID, INPROJ_N, 1.1f);
  dtfix_kernel<<<T_, 256, 0, stream>>>(hs_ln, in_proj_w, proj);
  conv_kernel<<<dim3(9, T_), 256, 0, stream>>>(proj, conv_w, conv_b, xbc);
  scanA_kernel<<<dim3(CH, MH, B_), 256, 0, stream>>>(xbc, proj, A_log, dt_bias, Dp,
                                                     y, Tbuf, lam, dec);
  scanB_kernel<<<dim3(MH, B_), 256, 0, stream>>>(xbc, Tbuf, lam, dec, y);
  gating_kernel<<<T_, 256, 0, stream>>>(y, proj, ssm_norm_w, g);
  gemm_kernel<<<dim3(16, 16), 256, 0, stream>>>(g, out_proj_w, h2, h2, nullptr,
                                                HID, HID, HID, 0.9f);

  // MLP
  rms_kernel<<<T_, 256, 0, stream>>>(h2, w_pre_ff_ln, hs2, nullptr);
  gemm_kernel<<<dim3(16, 128), 256, 0, stream>>>(hs2, gate_up_w, gu, nullptr, nullptr,
                                                 2 * INTER, HID, 2 * INTER, 1.0f);
  act_kernel<<<dim3(32, T_), 256, 0, stream>>>(gu, act);
  gemm_kernel<<<dim3(16, 16), 256, 0, stream>>>(act, down_w, outp, h2, nullptr,
                                                HID, INTER, HID, 0.8f);
}